// Round 9
// baseline (207.295 us; speedup 1.0000x reference)
//
#include <hip/hip_runtime.h>

#define NB 2048
#define NJ 22
#define ND 128
#define ROW4 (NJ * ND / 4)  // 704 float4 per i-row

typedef float f32x4 __attribute__((ext_vector_type(4)));

// out[b][i][j][e] = Y[b][j][e] - Y[b][i][e] + bias[e],  Y = src @ W^T
// R2 base + DOUBLE-STORE DIAGNOSTIC: epilogue runs twice (idempotent).
__global__ __launch_bounds__(256, 4) void see_kernel(
    const float* __restrict__ src, const float* __restrict__ W,
    const float* __restrict__ bias, float* __restrict__ out) {
  __shared__ float srcS[NJ * ND];  // [j][d]  (11 KB)
  __shared__ float YS[NJ * ND];    // [j][e]  (11 KB)

  const int b = blockIdx.x;
  const int t = threadIdx.x;
  const float* srcB = src + (size_t)b * NJ * ND;

  for (int idx = t; idx < NJ * ND / 4; idx += 256) {
    reinterpret_cast<f32x4*>(srcS)[idx] =
        reinterpret_cast<const f32x4*>(srcB)[idx];
  }

  const int e  = t & 127;  // output feature this thread owns
  const int dh = t >> 7;   // d-half (0/1)

  float w[64];
  {
    const f32x4* Wrow = reinterpret_cast<const f32x4*>(W + e * ND + dh * 64);
#pragma unroll
    for (int k = 0; k < 16; ++k) {
      f32x4 v = Wrow[k];
      w[4 * k + 0] = v.x; w[4 * k + 1] = v.y;
      w[4 * k + 2] = v.z; w[4 * k + 3] = v.w;
    }
  }
  __syncthreads();  // srcS ready

  for (int c = 0; c < 2; ++c) {  // two chunks of 11 rows: VGPR < 128
    float acc[11];
#pragma unroll
    for (int jj = 0; jj < 11; ++jj) {
      const int j = c * 11 + jj;
      const f32x4* s4 = reinterpret_cast<const f32x4*>(srcS + j * ND + dh * 64);
      float a = 0.f;
#pragma unroll
      for (int k = 0; k < 16; ++k) {
        f32x4 s = s4[k];  // wave-uniform address -> LDS broadcast
        a += s.x * w[4 * k + 0];
        a += s.y * w[4 * k + 1];
        a += s.z * w[4 * k + 2];
        a += s.w * w[4 * k + 3];
      }
      acc[jj] = a;
    }
    if (dh == 0) {
#pragma unroll
      for (int jj = 0; jj < 11; ++jj) YS[(c * 11 + jj) * ND + e] = acc[jj];
    }
    __syncthreads();
    if (dh == 1) {
#pragma unroll
      for (int jj = 0; jj < 11; ++jj) YS[(c * 11 + jj) * ND + e] += acc[jj];
    }
  }
  __syncthreads();  // YS complete

  // ---- epilogue ----
  const int e4 = t & 31;
  const int j0 = t >> 5;  // 0..7
  const f32x4* YS4 = reinterpret_cast<const f32x4*>(YS);
  const f32x4 bb4 = reinterpret_cast<const f32x4*>(bias)[e4];

  f32x4 yj0 = YS4[j0 * 32 + e4] + bb4;
  f32x4 yj1 = YS4[(j0 + 8) * 32 + e4] + bb4;
  f32x4 yj2 = {0.f, 0.f, 0.f, 0.f};
  if (j0 < 6) yj2 = YS4[(j0 + 16) * 32 + e4] + bb4;

  f32x4* outB4 = reinterpret_cast<f32x4*>(out + (size_t)b * NJ * NJ * ND);

  // PASS A (correct values)
  for (int ii = 0; ii < NJ; ++ii) {
    f32x4 yi = YS4[ii * 32 + e4];
    f32x4* outRow4 = outB4 + (size_t)ii * ROW4;
    __builtin_nontemporal_store(yj0 - yi, outRow4 + t);
    __builtin_nontemporal_store(yj1 - yi, outRow4 + t + 256);
    if (j0 < 6) __builtin_nontemporal_store(yj2 - yi, outRow4 + t + 512);
  }

  asm volatile("" ::: "memory");  // forbid dead-store elimination of pass A

  // PASS B (diagnostic: rewrites the SAME values -> output unchanged).
  // Pure-store phase: no GEMM, no barrier -> measures marginal store BW.
  for (int ii = 0; ii < NJ; ++ii) {
    f32x4 yi = YS4[ii * 32 + e4];
    f32x4* outRow4 = outB4 + (size_t)ii * ROW4;
    __builtin_nontemporal_store(yj0 - yi, outRow4 + t);
    __builtin_nontemporal_store(yj1 - yi, outRow4 + t + 256);
    if (j0 < 6) __builtin_nontemporal_store(yj2 - yi, outRow4 + t + 512);
  }
}

extern "C" void kernel_launch(void* const* d_in, const int* in_sizes, int n_in,
                              void* d_out, int out_size, void* d_ws, size_t ws_size,
                              hipStream_t stream) {
  const float* src  = (const float*)d_in[0];  // [2048, 22, 128] f32
  const float* W    = (const float*)d_in[1];  // [128, 128] f32, W[e][d]
  const float* bias = (const float*)d_in[2];  // [128] f32
  float* out = (float*)d_out;                 // [2048, 22, 22, 128] f32

  see_kernel<<<NB, 256, 0, stream>>>(src, W, bias, out);
}

// Round 10
// 117.733 us; speedup vs baseline: 1.7607x; 1.7607x over previous
//
#include <hip/hip_runtime.h>

#define NB 2048
#define NJ 22
#define ND 128
#define ROW4 (NJ * ND / 4)  // 704 float4 per i-row
#define BAT4 (NJ * ROW4)    // 15488 float4 per batch

typedef float f32x4 __attribute__((ext_vector_type(4)));

// out[b][i][j][e] = Y[b][j][e] - Y[b][i][e] + bias[e],  Y = src @ W^T
// R2 GEMM + band-contiguous epilogue: each wave writes a contiguous band of
// i-rows in ascending address order (fill-like per-wave store stream).
__global__ __launch_bounds__(256, 4) void see_kernel(
    const float* __restrict__ src, const float* __restrict__ W,
    const float* __restrict__ bias, float* __restrict__ out) {
  __shared__ float srcS[NJ * ND];  // [j][d]  (11 KB)
  __shared__ float YS[NJ * ND];    // [j][e]  (11 KB)

  const int b = blockIdx.x;
  const int t = threadIdx.x;
  const float* srcB = src + (size_t)b * NJ * ND;

  // ---- stage src[b] -> LDS ----
  for (int idx = t; idx < NJ * ND / 4; idx += 256) {
    reinterpret_cast<f32x4*>(srcS)[idx] =
        reinterpret_cast<const f32x4*>(srcB)[idx];
  }

  const int e  = t & 127;  // feature owned in GEMM
  const int dh = t >> 7;   // d-half (0/1)

  float w[64];
  {
    const f32x4* Wrow = reinterpret_cast<const f32x4*>(W + e * ND + dh * 64);
#pragma unroll
    for (int k = 0; k < 16; ++k) {
      f32x4 v = Wrow[k];
      w[4 * k + 0] = v.x; w[4 * k + 1] = v.y;
      w[4 * k + 2] = v.z; w[4 * k + 3] = v.w;
    }
  }
  __syncthreads();  // srcS ready

  for (int c = 0; c < 2; ++c) {  // two chunks of 11 rows: VGPR < 128
    float acc[11];
#pragma unroll
    for (int jj = 0; jj < 11; ++jj) {
      const int j = c * 11 + jj;
      const f32x4* s4 = reinterpret_cast<const f32x4*>(srcS + j * ND + dh * 64);
      float a = 0.f;
#pragma unroll
      for (int k = 0; k < 16; ++k) {
        f32x4 s = s4[k];  // wave-uniform address -> LDS broadcast
        a += s.x * w[4 * k + 0];
        a += s.y * w[4 * k + 1];
        a += s.z * w[4 * k + 2];
        a += s.w * w[4 * k + 3];
      }
      acc[jj] = a;
    }
    if (dh == 0) {
#pragma unroll
      for (int jj = 0; jj < 11; ++jj) YS[(c * 11 + jj) * ND + e] = acc[jj];
    }
    __syncthreads();
    if (dh == 1) {
#pragma unroll
      for (int jj = 0; jj < 11; ++jj) YS[(c * 11 + jj) * ND + e] += acc[jj];
    }
  }
  __syncthreads();  // YS complete

  // ---- band-contiguous epilogue ----
  // Within an i-row (704 float4), flat index q = k*64 + lane, k=0..10:
  //   jx = q>>5 = 2k + (lane>>5),  e4 = q&31 = lane&31.
  // Lane pre-loads its 11 yj values (+bias); wave wv owns a contiguous band
  // of i-rows and writes each row with 11 CONSECUTIVE 1KB store instructions.
  const int lane = t & 63;
  const int wv   = t >> 6;        // wave 0..3
  const int e4   = lane & 31;
  const int half = lane >> 5;     // 0/1
  const f32x4* YS4 = reinterpret_cast<const f32x4*>(YS);
  const f32x4 bb4 = reinterpret_cast<const f32x4*>(bias)[e4];

  f32x4 yj[11];
#pragma unroll
  for (int k = 0; k < 11; ++k)
    yj[k] = YS4[(2 * k + half) * 32 + e4] + bb4;  // bias folded into yj

  const int r0 = (wv < 2) ? 6 * wv : 12 + 5 * (wv - 2);  // 0,6,12,17
  const int rc = (wv < 2) ? 6 : 5;                        // band size

  f32x4* outB4 = reinterpret_cast<f32x4*>(out + (size_t)b * NJ * NJ * ND);

  for (int rr = 0; rr < rc; ++rr) {
    const int i = r0 + rr;
    f32x4 yi = YS4[i * 32 + e4];  // 2 lanes/addr -> free broadcast
    f32x4* rowp = outB4 + (size_t)i * ROW4 + lane;
#pragma unroll
    for (int k = 0; k < 11; ++k) rowp[k * 64] = yj[k] - yi;  // ascending 1KB runs
  }
}

extern "C" void kernel_launch(void* const* d_in, const int* in_sizes, int n_in,
                              void* d_out, int out_size, void* d_ws, size_t ws_size,
                              hipStream_t stream) {
  const float* src  = (const float*)d_in[0];  // [2048, 22, 128] f32
  const float* W    = (const float*)d_in[1];  // [128, 128] f32, W[e][d]
  const float* bias = (const float*)d_in[2];  // [128] f32
  float* out = (float*)d_out;                 // [2048, 22, 22, 128] f32

  see_kernel<<<NB, 256, 0, stream>>>(src, W, bias, out);
}

// Round 11
// 115.559 us; speedup vs baseline: 1.7938x; 1.0188x over previous
//
#include <hip/hip_runtime.h>

#define NB 2048
#define NJ 22
#define ND 128
#define NBAT 2
#define NBLK (NB / NBAT)     // 1024 blocks = 4 per CU (persistent)
#define JD (NJ * ND)         // 2816 floats per batch
#define ROW4 (JD / 4)        // 704 float4 per i-row

typedef float f32x4 __attribute__((ext_vector_type(4)));

// Raw barrier: drains LDS ops only; global stores stay in flight across it.
__device__ __forceinline__ void bar_lgkm() {
  asm volatile("s_waitcnt lgkmcnt(0)" ::: "memory");
  __builtin_amdgcn_s_barrier();
  __builtin_amdgcn_sched_barrier(0);
}

// out[b][i][j][e] = Y[b][j][e] - Y[b][i][e] + bias[e],  Y = src @ W^T
// R2's 16-wave/CU config + persistence: batch-1 GEMM runs under batch-0's
// draining stores; W/bias loaded once; no vmcnt drain inside the loop.
__global__ __launch_bounds__(256, 4) void see_kernel(
    const float* __restrict__ src, const float* __restrict__ W,
    const float* __restrict__ bias, float* __restrict__ out) {
  __shared__ float srcS[2][JD];  // 22.5 KB double-buffered src
  __shared__ float YS[JD];       // 11 KB

  const int t  = threadIdx.x;
  const int e  = t & 127;  // feature owned in GEMM
  const int dh = t >> 7;   // d-half (0/1)
  const int e4 = t & 31;   // epilogue float4 column
  const int j0 = t >> 5;   // epilogue rows {j0, j0+8, j0+16}
  const size_t b0 = (size_t)blockIdx.x * NBAT;

  // ---- W[e][dh*64..+63] + bias once per block (x2 batch reuse) ----
  float w[64];
  {
    const f32x4* Wrow = reinterpret_cast<const f32x4*>(W + e * ND + dh * 64);
#pragma unroll
    for (int k = 0; k < 16; ++k) {
      f32x4 v = Wrow[k];
      w[4 * k + 0] = v.x; w[4 * k + 1] = v.y;
      w[4 * k + 2] = v.z; w[4 * k + 3] = v.w;
    }
  }
  const f32x4 bb4 = reinterpret_cast<const f32x4*>(bias)[e4];

  // ---- prologue: stage src[b0] -> srcS[0] ----
  {
    const f32x4* g = reinterpret_cast<const f32x4*>(src + b0 * JD);
    f32x4* l = reinterpret_cast<f32x4*>(&srcS[0][0]);
    f32x4 r0 = g[t], r1 = g[t + 256], r2 = {0, 0, 0, 0};
    if (t < 192) r2 = g[t + 512];
    l[t] = r0; l[t + 256] = r1;
    if (t < 192) l[t + 512] = r2;
  }
  bar_lgkm();  // srcS[0] visible

  for (int bi = 0; bi < NBAT; ++bi) {
    const float* sC = &srcS[bi & 1][0];

    // ---- GEMM: two chunks of 11 j-rows (VGPR < 128) ----
    for (int c = 0; c < 2; ++c) {
      float acc[11];
#pragma unroll
      for (int jj = 0; jj < 11; ++jj) {
        const int j = c * 11 + jj;
        const f32x4* s4 = reinterpret_cast<const f32x4*>(sC + j * ND + dh * 64);
        float a = 0.f;
#pragma unroll
        for (int k = 0; k < 16; ++k) {
          f32x4 s = s4[k];  // wave-uniform address -> LDS broadcast
          a += s.x * w[4 * k + 0];
          a += s.y * w[4 * k + 1];
          a += s.z * w[4 * k + 2];
          a += s.w * w[4 * k + 3];
        }
        acc[jj] = a;
      }
      if (dh == 0) {
#pragma unroll
        for (int jj = 0; jj < 11; ++jj) YS[(c * 11 + jj) * ND + e] = acc[jj];
      }
      bar_lgkm();  // chunk's dh0 writes visible
      if (dh == 1) {
#pragma unroll
        for (int jj = 0; jj < 11; ++jj) YS[(c * 11 + jj) * ND + e] += acc[jj];
      }
      // next chunk touches disjoint YS rows -> no barrier here
    }
    bar_lgkm();  // YS complete

    // ---- prefetch next src tile to regs BEFORE the store burst ----
    f32x4 p0 = {0,0,0,0}, p1 = {0,0,0,0}, p2 = {0,0,0,0};
    const bool havePf = (bi + 1 < NBAT);
    if (havePf) {
      const f32x4* g = reinterpret_cast<const f32x4*>(src + (b0 + bi + 1) * JD);
      p0 = g[t]; p1 = g[t + 256];
      if (t < 192) p2 = g[t + 512];
    }
    __builtin_amdgcn_sched_barrier(0);  // pin prefetch loads before stores

    // ---- epilogue (R2-exact): NT stores, rows {j0, j0+8, j0+16} ----
    const f32x4* YS4 = reinterpret_cast<const f32x4*>(YS);
    f32x4 yj0 = YS4[j0 * 32 + e4] + bb4;
    f32x4 yj1 = YS4[(j0 + 8) * 32 + e4] + bb4;
    f32x4 yj2 = {0, 0, 0, 0};
    if (j0 < 6) yj2 = YS4[(j0 + 16) * 32 + e4] + bb4;

    f32x4* outB4 = reinterpret_cast<f32x4*>(out + (b0 + bi) * (size_t)NJ * JD);
    for (int ii = 0; ii < NJ; ++ii) {
      f32x4 yi = YS4[ii * 32 + e4];
      f32x4* outRow4 = outB4 + (size_t)ii * ROW4;
      __builtin_nontemporal_store(yj0 - yi, outRow4 + t);
      __builtin_nontemporal_store(yj1 - yi, outRow4 + t + 256);
      if (j0 < 6) __builtin_nontemporal_store(yj2 - yi, outRow4 + t + 512);
    }
    __builtin_amdgcn_sched_barrier(0);  // pin stores before srcS ds_writes

    // ---- write prefetched tile to the other srcS buffer ----
    if (havePf) {
      f32x4* l = reinterpret_cast<f32x4*>(&srcS[(bi + 1) & 1][0]);
      l[t] = p0; l[t + 256] = p1;
      if (t < 192) l[t + 512] = p2;
    }
    bar_lgkm();  // epilogue YS reads done + srcS[next] visible; stores in flight
  }
}

extern "C" void kernel_launch(void* const* d_in, const int* in_sizes, int n_in,
                              void* d_out, int out_size, void* d_ws, size_t ws_size,
                              hipStream_t stream) {
  const float* src  = (const float*)d_in[0];  // [2048, 22, 128] f32
  const float* W    = (const float*)d_in[1];  // [128, 128] f32, W[e][d]
  const float* bias = (const float*)d_in[2];  // [128] f32
  float* out = (float*)d_out;                 // [2048, 22, 22, 128] f32

  see_kernel<<<NBLK, 256, 0, stream>>>(src, W, bias, out);
}